// Round 12
// baseline (150.737 us; speedup 1.0000x reference)
//
#include <hip/hip_runtime.h>

// GCN: 2x GCNConv(128->128) + head (128->64), N=50000, E=800000.
// R11: non-temporal memory discipline. Scatter's streaming edge reads were
// capacity-evicting the accumulating csr/cnt lines from the XCD L2 (WRITE
// 32MB for 3.4MB useful). nt loads for all streamed reads (edges, csr rows),
// nt stores for gather outputs; cached writes only for csr/cnt/hs.

typedef _Float16 half8 __attribute__((ext_vector_type(8)));
typedef _Float16 half2v __attribute__((ext_vector_type(2)));
typedef float f32x4 __attribute__((ext_vector_type(4)));
typedef float f32x2 __attribute__((ext_vector_type(2)));
typedef int int4v __attribute__((ext_vector_type(4)));

constexpr int DIM = 128;
constexpr int NGRP = 8;
constexpr int CAP = 64;       // csr slots per node

// ---------------------------------------------------------------- prep ------
// blocks 0..31 : W2h = W2 @ Wh (f32, 128x64) -> ws
// block  32    : bconst = b2 @ Wh + bh
// blocks 33..40: pack W1 -> W1p fp16 fragments (B-frag layout, CT=8)
// blocks 41..48: zero cnt[n]
__global__ __launch_bounds__(256) void k_prep(
    const float* __restrict__ W1, const float* __restrict__ W2,
    const float* __restrict__ Wh, const float* __restrict__ b2,
    const float* __restrict__ bh, float* __restrict__ W2h,
    float* __restrict__ bconst, _Float16* __restrict__ W1p,
    int* __restrict__ cnt, int n) {
    int b = blockIdx.x, t = threadIdx.x;
    if (b < 32) {
        int gid = b * 256 + t;
        int r = gid >> 6, c = gid & 63;
        float s = 0.f;
        for (int k = 0; k < 128; ++k) s += W2[r * 128 + k] * Wh[k * 64 + c];
        W2h[gid] = s;
    } else if (b == 32) {
        if (t < 64) {
            float s = bh[t];
            for (int k = 0; k < 128; ++k) s += b2[k] * Wh[k * 64 + t];
            bconst[t] = s;
        }
    } else if (b < 41) {
        int q = (b - 33) * 256 + t;         // 0..2047 fragment chunks
        int lane = q & 63, ct = (q >> 6) & 7, ks = q >> 9;
        int kb = 32 * ks + 8 * (lane >> 4);
        int col = 16 * ct + (lane & 15);
        half8 v;
#pragma unroll
        for (int i = 0; i < 8; ++i) v[i] = (_Float16)W1[(kb + i) * 128 + col];
        *(half8*)&W1p[(size_t)q * 8] = v;
    } else {
        int4 z = make_int4(0, 0, 0, 0);
        int total4 = n >> 2;
        for (int i4 = (b - 41) * 256 + t; i4 < total4; i4 += 8 * 256)
            ((int4*)cnt)[i4] = z;
        if (b == 48) for (int i = (n & ~3) + t; i < n; i += 256) cnt[i] = 0;
    }
}

// ------------------------------- XCD-partitioned scatter (fixed bins) -------
// Streaming edge reads use nt loads so they don't evict accumulating
// csr/cnt lines from the owning XCD's L2.
__global__ __launch_bounds__(256) void k_scatter(
    const int* __restrict__ src, const int* __restrict__ dst,
    int* __restrict__ cnt, int* __restrict__ csr,
    const float* __restrict__ W2h, _Float16* __restrict__ W2p,
    int e, int chunk, int rsize) {
    if (blockIdx.x == gridDim.x - 1) {
        int q0 = threadIdx.x * 4;
#pragma unroll
        for (int j = 0; j < 4; ++j) {
            int q = q0 + j;                 // 0..1023, B-frag layout CT=4
            int lane = q & 63, ct = (q >> 6) & 3, ks = q >> 8;
            int kb = 32 * ks + 8 * (lane >> 4);
            int col = 16 * ct + (lane & 15);
            half8 v;
#pragma unroll
            for (int i = 0; i < 8; ++i) v[i] = (_Float16)W2h[(kb + i) * 64 + col];
            *(half8*)&W2p[(size_t)q * 8] = v;
        }
        return;
    }
    int g = blockIdx.x & (NGRP - 1);
    int c = blockIdx.x / NGRP;
    int lo = g * rsize, hi = lo + rsize;
    int base = c * chunk;
    int endi = min(base + chunk, e);
    for (int i = base + threadIdx.x * 4; i < endi; i += 1024) {
        if (i + 3 < endi) {
            int4v d4 = __builtin_nontemporal_load((const int4v*)(dst + i));
            int4v s4 = __builtin_nontemporal_load((const int4v*)(src + i));
            if (d4[0] >= lo && d4[0] < hi) {
                int p = atomicAdd(&cnt[d4[0]], 1);
                if (p < CAP) csr[(size_t)d4[0] * CAP + p] = s4[0];
            }
            if (d4[1] >= lo && d4[1] < hi) {
                int p = atomicAdd(&cnt[d4[1]], 1);
                if (p < CAP) csr[(size_t)d4[1] * CAP + p] = s4[1];
            }
            if (d4[2] >= lo && d4[2] < hi) {
                int p = atomicAdd(&cnt[d4[2]], 1);
                if (p < CAP) csr[(size_t)d4[2] * CAP + p] = s4[2];
            }
            if (d4[3] >= lo && d4[3] < hi) {
                int p = atomicAdd(&cnt[d4[3]], 1);
                if (p < CAP) csr[(size_t)d4[3] * CAP + p] = s4[3];
            }
        } else {
            for (int k = i; k < endi; ++k) {
                int d = __builtin_nontemporal_load(dst + k);
                if (d >= lo && d < hi) {
                    int p = atomicAdd(&cnt[d], 1);
                    if (p < CAP) csr[(size_t)d * CAP + p] =
                        __builtin_nontemporal_load(src + k);
                }
            }
        }
    }
}

// ----------------------------------------------------------------- dinv -----
__global__ __launch_bounds__(256) void k_dinv(const int* __restrict__ cnt,
                                              float* __restrict__ dinv, int n) {
    int i = blockIdx.x * 256 + threadIdx.x;
    if (i < n) dinv[i] = rsqrtf((float)(cnt[i] + 1));
}

// ------------------------------------------------------------ MFMA GEMM -----
// C[n,NCOL] (fp16) = rowscale(A[n,128] @ B[128,NCOL]); produces pre-scaled hs.
template <int NCOL, bool AF16>
__global__ __launch_bounds__(256) void k_gemm(
    const void* __restrict__ Asrc, const _Float16* __restrict__ Bp,
    const float* __restrict__ rscale, _Float16* __restrict__ Cout, int n) {
    constexpr int CT = NCOL / 16;          // 8 or 4
    constexpr int BCHUNK = 4 * CT * 64;
    __shared__ _Float16 Bs[BCHUNK * 8];    // 32KB / 16KB
    __shared__ _Float16 As[8192];          // 16KB, reused for epilogue

    int tid = threadIdx.x;
    int row0 = blockIdx.x * 64;

    {   // stage packed B linearly (conflict-free)
        const uint4* sp = (const uint4*)Bp;
        uint4* dp = (uint4*)Bs;
        for (int i = tid; i < BCHUNK; i += 256) dp[i] = sp[i];
    }
    // stage A in fragment order: chunk q = (w*4+ks)*64 + lane
    for (int q = tid; q < 1024; q += 256) {
        int l = q & 63, s = q >> 6;
        int w = s >> 2, ks = s & 3;
        int row = row0 + 16 * w + (l & 15);
        int k0 = 32 * ks + 8 * (l >> 4);
        half8 v;
#pragma unroll
        for (int i = 0; i < 8; ++i) v[i] = (_Float16)0.f;
        if (row < n) {
            if constexpr (AF16) {
                v = *(const half8*)((const _Float16*)Asrc + (size_t)row * 128 + k0);
            } else {
                const float* p = (const float*)Asrc + (size_t)row * 128 + k0;
                f32x4 lo = *(const f32x4*)p;
                f32x4 hi = *(const f32x4*)(p + 4);
                v[0] = (_Float16)lo[0]; v[1] = (_Float16)lo[1];
                v[2] = (_Float16)lo[2]; v[3] = (_Float16)lo[3];
                v[4] = (_Float16)hi[0]; v[5] = (_Float16)hi[1];
                v[6] = (_Float16)hi[2]; v[7] = (_Float16)hi[3];
            }
        }
        *(half8*)&As[(size_t)q * 8] = v;
    }
    __syncthreads();

    int w = tid >> 6, lane = tid & 63;
    f32x4 acc[CT];
#pragma unroll
    for (int ct = 0; ct < CT; ++ct) acc[ct] = (f32x4){0.f, 0.f, 0.f, 0.f};
#pragma unroll
    for (int ks = 0; ks < 4; ++ks) {
        half8 a = *(const half8*)&As[((w * 4 + ks) * 64 + lane) * 8];
#pragma unroll
        for (int ct = 0; ct < CT; ++ct) {
            half8 b = *(const half8*)&Bs[((ks * CT + ct) * 64 + lane) * 8];
            acc[ct] = __builtin_amdgcn_mfma_f32_16x16x32_f16(a, b, acc[ct], 0, 0, 0);
        }
    }
    __syncthreads();   // reuse As as [64][NCOL] fp16 epilogue buffer

    int rg = lane >> 4, cl = lane & 15;
    float sc[4];
#pragma unroll
    for (int r = 0; r < 4; ++r) {
        int row = row0 + 16 * w + 4 * rg + r;
        sc[r] = (row < n) ? rscale[row] : 0.f;
    }
#pragma unroll
    for (int ct = 0; ct < CT; ++ct)
#pragma unroll
        for (int r = 0; r < 4; ++r)
            As[(16 * w + 4 * rg + r) * NCOL + 16 * ct + cl] =
                (_Float16)(acc[ct][r] * sc[r]);
    __syncthreads();

    constexpr int CHROW = NCOL / 8;
    for (int c = tid; c < 64 * CHROW; c += 256) {
        int r = c / CHROW;
        int row = row0 + r;
        if (row < n)
            *(half8*)(Cout + (size_t)row * NCOL + (size_t)(c - r * CHROW) * 8) =
                *(const half8*)&As[c * 8];
    }
}

// ------------------------------------------------------- gather layer 1 -----
// 64 lanes/node, 2 fp16 feats/lane. Pure unweighted sum of pre-scaled rows.
// csr rows read nt (stream-once), hs reads cached (hot), hA written nt.
__global__ __launch_bounds__(256) void k_gather_l1(
    const int* __restrict__ cnt, const float* __restrict__ dinv,
    const int* __restrict__ csr, const _Float16* __restrict__ hs,
    const float* __restrict__ b1, _Float16* __restrict__ hA, int n) {
    int g = (blockIdx.x * 256 + threadIdx.x) >> 6;
    int lane = threadIdx.x & 63;
    if (g >= n) return;
    const half2v* h2 = (const half2v*)hs;
    int deg = cnt[g];
    float dg = dinv[g];
    half2v hv = h2[(size_t)g * 64 + lane];
    float a0 = (float)hv[0], a1 = (float)hv[1];
    float c0 = 0.f, c1 = 0.f;
    const int* row = csr + (size_t)g * CAP;
    int j = 0;
    for (; j + 4 <= deg; j += 4) {
        int4v s4 = __builtin_nontemporal_load((const int4v*)(row + j));
        half2v v0 = h2[(size_t)s4[0] * 64 + lane];
        half2v v1 = h2[(size_t)s4[1] * 64 + lane];
        half2v v2 = h2[(size_t)s4[2] * 64 + lane];
        half2v v3 = h2[(size_t)s4[3] * 64 + lane];
        a0 += (float)v0[0]; a1 += (float)v0[1];
        c0 += (float)v1[0]; c1 += (float)v1[1];
        a0 += (float)v2[0]; a1 += (float)v2[1];
        c0 += (float)v3[0]; c1 += (float)v3[1];
    }
    for (; j < deg; ++j) {
        int sv = __builtin_nontemporal_load(row + j);
        half2v v0 = h2[(size_t)sv * 64 + lane];
        a0 += (float)v0[0]; a1 += (float)v0[1];
    }
    f32x2 bb = *(const f32x2*)(b1 + lane * 2);
    half2v o;
    o[0] = (_Float16)fmaxf((a0 + c0) * dg + bb[0], 0.f);
    o[1] = (_Float16)fmaxf((a1 + c1) * dg + bb[1], 0.f);
    __builtin_nontemporal_store(o, (half2v*)(hA + (size_t)g * 128 + lane * 2));
}

// ------------------------------------------------------- gather layer 2 -----
// 32 lanes/node, 2 fp16 feats/lane; epilogue *dinv_g +bconst, f32 out (nt).
__global__ __launch_bounds__(256) void k_gather_l2(
    const int* __restrict__ cnt, const float* __restrict__ dinv,
    const int* __restrict__ csr, const _Float16* __restrict__ hs,
    const float* __restrict__ bconst, float* __restrict__ outp, int n) {
    int g = (blockIdx.x * 256 + threadIdx.x) >> 5;
    int lane = threadIdx.x & 31;
    if (g >= n) return;
    const half2v* hp = (const half2v*)hs;
    int deg = cnt[g];
    float dg = dinv[g];
    half2v hv = hp[(size_t)g * 32 + lane];
    float a0 = (float)hv[0], a1 = (float)hv[1];
    float c0 = 0.f, c1 = 0.f;
    const int* row = csr + (size_t)g * CAP;
    int j = 0;
    for (; j + 4 <= deg; j += 4) {
        int4v s4 = __builtin_nontemporal_load((const int4v*)(row + j));
        half2v v0 = hp[(size_t)s4[0] * 32 + lane];
        half2v v1 = hp[(size_t)s4[1] * 32 + lane];
        half2v v2 = hp[(size_t)s4[2] * 32 + lane];
        half2v v3 = hp[(size_t)s4[3] * 32 + lane];
        a0 += (float)v0[0]; a1 += (float)v0[1];
        c0 += (float)v1[0]; c1 += (float)v1[1];
        a0 += (float)v2[0]; a1 += (float)v2[1];
        c0 += (float)v3[0]; c1 += (float)v3[1];
    }
    for (; j < deg; ++j) {
        int sv = __builtin_nontemporal_load(row + j);
        half2v v0 = hp[(size_t)sv * 32 + lane];
        a0 += (float)v0[0]; a1 += (float)v0[1];
    }
    f32x2 bc = *(const f32x2*)(bconst + lane * 2);
    f32x2 ov;
    ov[0] = (a0 + c0) * dg + bc[0];
    ov[1] = (a1 + c1) * dg + bc[1];
    __builtin_nontemporal_store(ov, (f32x2*)(outp + (size_t)g * 64 + lane * 2));
}

// --------------------------------------------------------------- launch -----
extern "C" void kernel_launch(void* const* d_in, const int* in_sizes, int n_in,
                              void* d_out, int out_size, void* d_ws, size_t ws_size,
                              hipStream_t stream) {
    const float* x  = (const float*)d_in[0];
    const int*   ei = (const int*)d_in[1];
    const float* W1 = (const float*)d_in[2];
    const float* b1 = (const float*)d_in[3];
    const float* W2 = (const float*)d_in[4];
    const float* b2 = (const float*)d_in[5];
    const float* Wh = (const float*)d_in[6];
    const float* bh = (const float*)d_in[7];
    float* out = (float*)d_out;

    const int n = in_sizes[0] / DIM;       // 50000
    const int e = in_sizes[1] / 2;         // 800000
    const int* src = ei;
    const int* dst = ei + e;

    char* wsp = (char*)d_ws;
    auto alloc = [&](size_t bytes) {
        char* p = wsp;
        wsp += (bytes + 255) & ~(size_t)255;
        return p;
    };
    int*       cnt    = (int*)alloc((size_t)n * 4);
    float*     dinv   = (float*)alloc((size_t)n * 4);
    float*     W2h    = (float*)alloc(8192 * 4);
    float*     bconst = (float*)alloc(64 * 4);
    _Float16*  W1p    = (_Float16*)alloc(16384 * 2);
    _Float16*  W2p    = (_Float16*)alloc(8192 * 2);
    int*       csr    = (int*)alloc((size_t)n * CAP * 4);   // 12.8MB bins
    _Float16*  hbuf   = (_Float16*)alloc((size_t)n * 128 * 2);
    _Float16*  hA     = (_Float16*)alloc((size_t)n * 128 * 2);
    _Float16*  h2     = (_Float16*)alloc((size_t)n * 64 * 2);

    int gbGemm = (n + 63) / 64;            // 782
    int gbN    = (n + 255) / 256;          // 196
    int gbW64  = (int)(((size_t)n * 64 + 255) / 256);  // 12500
    int gbW32  = (int)(((size_t)n * 32 + 255) / 256);  // 6250

    // partitioned edge-pass geometry: 256 chunks x 8 groups
    const int CH = 256;
    int chunkE = ((e + CH - 1) / CH + 3) & ~3;          // 3128
    int rsize  = (n + NGRP - 1) / NGRP;                 // 6250
    int gbPart = CH * NGRP;                             // 2048

    k_prep<<<49, 256, 0, stream>>>(W1, W2, Wh, b2, bh, W2h, bconst, W1p, cnt, n);
    k_scatter<<<gbPart + 1, 256, 0, stream>>>(src, dst, cnt, csr, W2h, W2p,
                                              e, chunkE, rsize);
    k_dinv<<<gbN, 256, 0, stream>>>(cnt, dinv, n);

    k_gemm<128, false><<<gbGemm, 256, 0, stream>>>((const void*)x, W1p, dinv, hbuf, n);
    k_gather_l1<<<gbW64, 256, 0, stream>>>(cnt, dinv, csr, hbuf, b1, hA, n);
    k_gemm<64, true><<<gbGemm, 256, 0, stream>>>((const void*)hA, W2p, dinv, h2, n);
    k_gather_l2<<<gbW32, 256, 0, stream>>>(cnt, dinv, csr, h2, bconst, out, n);
}

// Round 13
// 112.777 us; speedup vs baseline: 1.3366x; 1.3366x over previous
//
#include <hip/hip_runtime.h>

// GCN: 2x GCNConv(128->128) + head (128->64), N=50000, E=800000.
// R12: two-level bucketed CSR build. Phase 1 (k_bucket): LDS-counted dst
// buckets (dst>>8, 196 buckets), ONE global atomic per bucket per block
// (38k total vs 800k), pairs written to per-bucket runs. Phase 2 (k_bins):
// one block per bucket; per-node positions via LDS atomics; csr writes land
// in a 64KB L2-local region; writes cnt+dinv. Gathers/GEMMs = R10 (proven;
// R11's nontemporal experiment reverted -- it cost +15us).

typedef _Float16 half8 __attribute__((ext_vector_type(8)));
typedef _Float16 half2v __attribute__((ext_vector_type(2)));
typedef float f32x4 __attribute__((ext_vector_type(4)));

constexpr int DIM = 128;
constexpr int CAP = 64;       // csr slots per node
constexpr int BCAP = 5120;    // pairs per bucket (lambda=4082, +16 sigma)

// ---------------------------------------------------------------- prep ------
// blocks 0..31 : W2h = W2 @ Wh (f32, 128x64) -> ws
// block  32    : bconst = b2 @ Wh + bh ; zero bucket cursors
// blocks 33..40: pack W1 -> W1p fp16 fragments (B-frag layout, CT=8)
__global__ __launch_bounds__(256) void k_prep(
    const float* __restrict__ W1, const float* __restrict__ W2,
    const float* __restrict__ Wh, const float* __restrict__ b2,
    const float* __restrict__ bh, float* __restrict__ W2h,
    float* __restrict__ bconst, _Float16* __restrict__ W1p,
    int* __restrict__ cursor, int nb) {
    int b = blockIdx.x, t = threadIdx.x;
    if (b < 32) {
        int gid = b * 256 + t;
        int r = gid >> 6, c = gid & 63;
        float s = 0.f;
        for (int k = 0; k < 128; ++k) s += W2[r * 128 + k] * Wh[k * 64 + c];
        W2h[gid] = s;
    } else if (b == 32) {
        if (t < 64) {
            float s = bh[t];
            for (int k = 0; k < 128; ++k) s += b2[k] * Wh[k * 64 + t];
            bconst[t] = s;
        }
        if (t < nb) cursor[t] = 0;
    } else {
        int q = (b - 33) * 256 + t;         // 0..2047 fragment chunks
        int lane = q & 63, ct = (q >> 6) & 7, ks = q >> 9;
        int kb = 32 * ks + 8 * (lane >> 4);
        int col = 16 * ct + (lane & 15);
        half8 v;
#pragma unroll
        for (int i = 0; i < 8; ++i) v[i] = (_Float16)W1[(kb + i) * 128 + col];
        *(half8*)&W1p[(size_t)q * 8] = v;
    }
}

// ------------------------------------------- phase 1: bucket partition ------
// Each block: 4096 edges. Pass A counts per-bucket in LDS; one global
// atomicAdd per non-empty bucket reserves a contiguous run; pass B re-reads
// (L2-hot) and writes (src,dst) pairs into the run via LDS position atomics.
// Last block packs W2p from W2h instead.
__global__ __launch_bounds__(256) void k_bucket(
    const int* __restrict__ src, const int* __restrict__ dst,
    int* __restrict__ cursor, int2* __restrict__ pairs,
    const float* __restrict__ W2h, _Float16* __restrict__ W2p, int e) {
    if (blockIdx.x == gridDim.x - 1) {
        int q0 = threadIdx.x * 4;
#pragma unroll
        for (int j = 0; j < 4; ++j) {
            int q = q0 + j;                 // 0..1023, B-frag layout CT=4
            int lane = q & 63, ct = (q >> 6) & 3, ks = q >> 8;
            int kb = 32 * ks + 8 * (lane >> 4);
            int col = 16 * ct + (lane & 15);
            half8 v;
#pragma unroll
            for (int i = 0; i < 8; ++i) v[i] = (_Float16)W2h[(kb + i) * 64 + col];
            *(half8*)&W2p[(size_t)q * 8] = v;
        }
        return;
    }
    __shared__ int lcnt[256];
    __shared__ int lbase[256];
    int tid = threadIdx.x;
    int base = blockIdx.x * 4096;
    int endi = min(base + 4096, e);

    for (int i = tid; i < 256; i += 256) lcnt[i] = 0;
    __syncthreads();

    // pass A: count buckets
    for (int i = base + tid * 4; i < endi; i += 1024) {
        if (i + 3 < endi) {
            int4 d4 = *(const int4*)(dst + i);
            atomicAdd(&lcnt[d4.x >> 8], 1);
            atomicAdd(&lcnt[d4.y >> 8], 1);
            atomicAdd(&lcnt[d4.z >> 8], 1);
            atomicAdd(&lcnt[d4.w >> 8], 1);
        } else {
            for (int k = i; k < endi; ++k) atomicAdd(&lcnt[dst[k] >> 8], 1);
        }
    }
    __syncthreads();

    // reserve global runs (one atomic per non-empty bucket)
    if (tid < 256) {
        int c = lcnt[tid];
        lbase[tid] = (c > 0) ? atomicAdd(&cursor[tid], c) : 0;
    }
    __syncthreads();
    for (int i = tid; i < 256; i += 256) lcnt[i] = 0;   // reuse as position
    __syncthreads();

    // pass B: write pairs
    for (int i = base + tid * 4; i < endi; i += 1024) {
        if (i + 3 < endi) {
            int4 d4 = *(const int4*)(dst + i);
            int4 s4 = *(const int4*)(src + i);
            {
                int bk = d4.x >> 8;
                int gi = lbase[bk] + atomicAdd(&lcnt[bk], 1);
                if (gi < BCAP) pairs[(size_t)bk * BCAP + gi] = make_int2(s4.x, d4.x);
            }
            {
                int bk = d4.y >> 8;
                int gi = lbase[bk] + atomicAdd(&lcnt[bk], 1);
                if (gi < BCAP) pairs[(size_t)bk * BCAP + gi] = make_int2(s4.y, d4.y);
            }
            {
                int bk = d4.z >> 8;
                int gi = lbase[bk] + atomicAdd(&lcnt[bk], 1);
                if (gi < BCAP) pairs[(size_t)bk * BCAP + gi] = make_int2(s4.z, d4.z);
            }
            {
                int bk = d4.w >> 8;
                int gi = lbase[bk] + atomicAdd(&lcnt[bk], 1);
                if (gi < BCAP) pairs[(size_t)bk * BCAP + gi] = make_int2(s4.w, d4.w);
            }
        } else {
            for (int k = i; k < endi; ++k) {
                int d = dst[k];
                int bk = d >> 8;
                int gi = lbase[bk] + atomicAdd(&lcnt[bk], 1);
                if (gi < BCAP) pairs[(size_t)bk * BCAP + gi] = make_int2(src[k], d);
            }
        }
    }
}

// ------------------------------------------------ phase 2: fine binning -----
// One block per bucket (256 nodes). LDS position atomics; csr writes stay
// in a 64KB region (L2-local, full-line writeback). Writes cnt + dinv.
__global__ __launch_bounds__(256) void k_bins(
    const int2* __restrict__ pairs, const int* __restrict__ cursor,
    int* __restrict__ csr, int* __restrict__ cnt, float* __restrict__ dinv,
    int n) {
    __shared__ int lcnt[256];
    int bkt = blockIdx.x;
    int tid = threadIdx.x;
    lcnt[tid] = 0;
    __syncthreads();
    int total = min(cursor[bkt], BCAP);
    const int2* run = pairs + (size_t)bkt * BCAP;
    for (int i = tid; i < total; i += 256) {
        int2 p = run[i];
        int pos = atomicAdd(&lcnt[p.y & 255], 1);
        if (pos < CAP) csr[(size_t)p.y * CAP + pos] = p.x;
    }
    __syncthreads();
    int node = (bkt << 8) + tid;
    if (node < n) {
        int c = min(lcnt[tid], CAP);
        cnt[node] = c;
        dinv[node] = rsqrtf((float)(lcnt[tid] + 1));
    }
}

// ------------------------------------------------------------ MFMA GEMM -----
// C[n,NCOL] (fp16) = rowscale(A[n,128] @ B[128,NCOL]); produces pre-scaled hs.
template <int NCOL, bool AF16>
__global__ __launch_bounds__(256) void k_gemm(
    const void* __restrict__ Asrc, const _Float16* __restrict__ Bp,
    const float* __restrict__ rscale, _Float16* __restrict__ Cout, int n) {
    constexpr int CT = NCOL / 16;          // 8 or 4
    constexpr int BCHUNK = 4 * CT * 64;
    __shared__ _Float16 Bs[BCHUNK * 8];    // 32KB / 16KB
    __shared__ _Float16 As[8192];          // 16KB, reused for epilogue

    int tid = threadIdx.x;
    int row0 = blockIdx.x * 64;

    {   // stage packed B linearly (conflict-free)
        const uint4* sp = (const uint4*)Bp;
        uint4* dp = (uint4*)Bs;
        for (int i = tid; i < BCHUNK; i += 256) dp[i] = sp[i];
    }
    // stage A in fragment order: chunk q = (w*4+ks)*64 + lane
    for (int q = tid; q < 1024; q += 256) {
        int l = q & 63, s = q >> 6;
        int w = s >> 2, ks = s & 3;
        int row = row0 + 16 * w + (l & 15);
        int k0 = 32 * ks + 8 * (l >> 4);
        half8 v;
#pragma unroll
        for (int i = 0; i < 8; ++i) v[i] = (_Float16)0.f;
        if (row < n) {
            if constexpr (AF16) {
                v = *(const half8*)((const _Float16*)Asrc + (size_t)row * 128 + k0);
            } else {
                const float* p = (const float*)Asrc + (size_t)row * 128 + k0;
                f32x4 lo = *(const f32x4*)p;
                f32x4 hi = *(const f32x4*)(p + 4);
                v[0] = (_Float16)lo[0]; v[1] = (_Float16)lo[1];
                v[2] = (_Float16)lo[2]; v[3] = (_Float16)lo[3];
                v[4] = (_Float16)hi[0]; v[5] = (_Float16)hi[1];
                v[6] = (_Float16)hi[2]; v[7] = (_Float16)hi[3];
            }
        }
        *(half8*)&As[(size_t)q * 8] = v;
    }
    __syncthreads();

    int w = tid >> 6, lane = tid & 63;
    f32x4 acc[CT];
#pragma unroll
    for (int ct = 0; ct < CT; ++ct) acc[ct] = (f32x4){0.f, 0.f, 0.f, 0.f};
#pragma unroll
    for (int ks = 0; ks < 4; ++ks) {
        half8 a = *(const half8*)&As[((w * 4 + ks) * 64 + lane) * 8];
#pragma unroll
        for (int ct = 0; ct < CT; ++ct) {
            half8 b = *(const half8*)&Bs[((ks * CT + ct) * 64 + lane) * 8];
            acc[ct] = __builtin_amdgcn_mfma_f32_16x16x32_f16(a, b, acc[ct], 0, 0, 0);
        }
    }
    __syncthreads();   // reuse As as [64][NCOL] fp16 epilogue buffer

    int rg = lane >> 4, cl = lane & 15;
    float sc[4];
#pragma unroll
    for (int r = 0; r < 4; ++r) {
        int row = row0 + 16 * w + 4 * rg + r;
        sc[r] = (row < n) ? rscale[row] : 0.f;
    }
#pragma unroll
    for (int ct = 0; ct < CT; ++ct)
#pragma unroll
        for (int r = 0; r < 4; ++r)
            As[(16 * w + 4 * rg + r) * NCOL + 16 * ct + cl] =
                (_Float16)(acc[ct][r] * sc[r]);
    __syncthreads();

    constexpr int CHROW = NCOL / 8;
    for (int c = tid; c < 64 * CHROW; c += 256) {
        int r = c / CHROW;
        int row = row0 + r;
        if (row < n)
            *(half8*)(Cout + (size_t)row * NCOL + (size_t)(c - r * CHROW) * 8) =
                *(const half8*)&As[c * 8];
    }
}

// ------------------------------------------------------- gather layer 1 -----
// 64 lanes/node, 2 fp16 feats/lane. Pure unweighted sum of pre-scaled rows;
// epilogue: *dinv_g, +b1, relu, fp16 out. (Plain cached loads -- R10 proven.)
__global__ __launch_bounds__(256) void k_gather_l1(
    const int* __restrict__ cnt, const float* __restrict__ dinv,
    const int* __restrict__ csr, const _Float16* __restrict__ hs,
    const float* __restrict__ b1, _Float16* __restrict__ hA, int n) {
    int g = (blockIdx.x * 256 + threadIdx.x) >> 6;
    int lane = threadIdx.x & 63;
    if (g >= n) return;
    const half2v* h2 = (const half2v*)hs;
    int deg = cnt[g];
    float dg = dinv[g];
    half2v hv = h2[(size_t)g * 64 + lane];
    float a0 = (float)hv[0], a1 = (float)hv[1];
    float c0 = 0.f, c1 = 0.f;
    const int* row = csr + (size_t)g * CAP;
    int j = 0;
    for (; j + 4 <= deg; j += 4) {
        int4 s4 = *(const int4*)(row + j);
        half2v v0 = h2[(size_t)s4.x * 64 + lane];
        half2v v1 = h2[(size_t)s4.y * 64 + lane];
        half2v v2 = h2[(size_t)s4.z * 64 + lane];
        half2v v3 = h2[(size_t)s4.w * 64 + lane];
        a0 += (float)v0[0]; a1 += (float)v0[1];
        c0 += (float)v1[0]; c1 += (float)v1[1];
        a0 += (float)v2[0]; a1 += (float)v2[1];
        c0 += (float)v3[0]; c1 += (float)v3[1];
    }
    for (; j < deg; ++j) {
        half2v v0 = h2[(size_t)row[j] * 64 + lane];
        a0 += (float)v0[0]; a1 += (float)v0[1];
    }
    float2 bb = *(const float2*)(b1 + lane * 2);
    half2v o;
    o[0] = (_Float16)fmaxf((a0 + c0) * dg + bb.x, 0.f);
    o[1] = (_Float16)fmaxf((a1 + c1) * dg + bb.y, 0.f);
    *(half2v*)(hA + (size_t)g * 128 + lane * 2) = o;
}

// ------------------------------------------------------- gather layer 2 -----
// 32 lanes/node, 2 fp16 feats/lane; epilogue *dinv_g +bconst, f32 out.
__global__ __launch_bounds__(256) void k_gather_l2(
    const int* __restrict__ cnt, const float* __restrict__ dinv,
    const int* __restrict__ csr, const _Float16* __restrict__ hs,
    const float* __restrict__ bconst, float* __restrict__ outp, int n) {
    int g = (blockIdx.x * 256 + threadIdx.x) >> 5;
    int lane = threadIdx.x & 31;
    if (g >= n) return;
    const half2v* hp = (const half2v*)hs;
    int deg = cnt[g];
    float dg = dinv[g];
    half2v hv = hp[(size_t)g * 32 + lane];
    float a0 = (float)hv[0], a1 = (float)hv[1];
    float c0 = 0.f, c1 = 0.f;
    const int* row = csr + (size_t)g * CAP;
    int j = 0;
    for (; j + 4 <= deg; j += 4) {
        int4 s4 = *(const int4*)(row + j);
        half2v v0 = hp[(size_t)s4.x * 32 + lane];
        half2v v1 = hp[(size_t)s4.y * 32 + lane];
        half2v v2 = hp[(size_t)s4.z * 32 + lane];
        half2v v3 = hp[(size_t)s4.w * 32 + lane];
        a0 += (float)v0[0]; a1 += (float)v0[1];
        c0 += (float)v1[0]; c1 += (float)v1[1];
        a0 += (float)v2[0]; a1 += (float)v2[1];
        c0 += (float)v3[0]; c1 += (float)v3[1];
    }
    for (; j < deg; ++j) {
        half2v v0 = hp[(size_t)row[j] * 32 + lane];
        a0 += (float)v0[0]; a1 += (float)v0[1];
    }
    float2 bc = *(const float2*)(bconst + lane * 2);
    *(float2*)(outp + (size_t)g * 64 + lane * 2) =
        make_float2((a0 + c0) * dg + bc.x, (a1 + c1) * dg + bc.y);
}

// --------------------------------------------------------------- launch -----
extern "C" void kernel_launch(void* const* d_in, const int* in_sizes, int n_in,
                              void* d_out, int out_size, void* d_ws, size_t ws_size,
                              hipStream_t stream) {
    const float* x  = (const float*)d_in[0];
    const int*   ei = (const int*)d_in[1];
    const float* W1 = (const float*)d_in[2];
    const float* b1 = (const float*)d_in[3];
    const float* W2 = (const float*)d_in[4];
    const float* b2 = (const float*)d_in[5];
    const float* Wh = (const float*)d_in[6];
    const float* bh = (const float*)d_in[7];
    float* out = (float*)d_out;

    const int n = in_sizes[0] / DIM;       // 50000
    const int e = in_sizes[1] / 2;         // 800000
    const int* src = ei;
    const int* dst = ei + e;
    const int nb = (n + 255) >> 8;         // 196 buckets

    char* wsp = (char*)d_ws;
    auto alloc = [&](size_t bytes) {
        char* p = wsp;
        wsp += (bytes + 255) & ~(size_t)255;
        return p;
    };
    int*       cnt    = (int*)alloc((size_t)n * 4);
    float*     dinv   = (float*)alloc((size_t)n * 4);
    float*     W2h    = (float*)alloc(8192 * 4);
    float*     bconst = (float*)alloc(64 * 4);
    _Float16*  W1p    = (_Float16*)alloc(16384 * 2);
    _Float16*  W2p    = (_Float16*)alloc(8192 * 2);
    int*       cursor = (int*)alloc((size_t)nb * 4);
    int2*      pairs  = (int2*)alloc((size_t)nb * BCAP * 8);  // ~8MB
    int*       csr    = (int*)alloc((size_t)n * CAP * 4);     // 12.8MB bins
    _Float16*  hbuf   = (_Float16*)alloc((size_t)n * 128 * 2);
    _Float16*  hA     = (_Float16*)alloc((size_t)n * 128 * 2);
    _Float16*  h2     = (_Float16*)alloc((size_t)n * 64 * 2);

    int gbGemm = (n + 63) / 64;            // 782
    int gbBkt  = (e + 4095) / 4096 + 1;    // 196 + W2p-pack block
    int gbW64  = (int)(((size_t)n * 64 + 255) / 256);  // 12500
    int gbW32  = (int)(((size_t)n * 32 + 255) / 256);  // 6250

    k_prep<<<41, 256, 0, stream>>>(W1, W2, Wh, b2, bh, W2h, bconst, W1p,
                                   cursor, nb);
    k_bucket<<<gbBkt, 256, 0, stream>>>(src, dst, cursor, pairs, W2h, W2p, e);
    k_bins<<<nb, 256, 0, stream>>>(pairs, cursor, csr, cnt, dinv, n);

    k_gemm<128, false><<<gbGemm, 256, 0, stream>>>((const void*)x, W1p, dinv, hbuf, n);
    k_gather_l1<<<gbW64, 256, 0, stream>>>(cnt, dinv, csr, hbuf, b1, hA, n);
    k_gemm<64, true><<<gbGemm, 256, 0, stream>>>((const void*)hA, W2p, dinv, h2, n);
    k_gather_l2<<<gbW32, 256, 0, stream>>>(cnt, dinv, csr, h2, bconst, out, n);
}